// Round 11
// baseline (242.626 us; speedup 1.0000x reference)
//
#include <hip/hip_runtime.h>

typedef __bf16 bf16;
typedef __bf16 bf16x8 __attribute__((ext_vector_type(8)));
typedef float f32x4 __attribute__((ext_vector_type(4)));

__device__ __forceinline__ void gll16(const void* g, void* l) {
    __builtin_amdgcn_global_load_lds((const __attribute__((address_space(1))) void*)g,
                                     (__attribute__((address_space(3))) void*)l, 16, 0, 0);
}

// gelu via sigmoid identity: 0.5(1+tanh(u)) == sigmoid(2u). 8 VALU ops, no branches.
__device__ __forceinline__ float gelu_f(float v) {
    float x2 = v * v;
    float sn = v * fmaf(-0.0713540072f, x2, -1.5957691216f);   // -2u
    float e  = __expf(sn);
    return v * __builtin_amdgcn_rcpf(1.0f + e);
}

// ---------------- prep: 4 weight transposes (blocks 0..1535) + dual LN (blocks 1536..2047) ----
__launch_bounds__(256)
__global__ void prep_kernel(const float* __restrict__ wqkv, const float* __restrict__ wout,
                            const float* __restrict__ wff1, const float* __restrict__ wff2,
                            bf16* __restrict__ wqkvT, bf16* __restrict__ woutT,
                            bf16* __restrict__ wff1T, bf16* __restrict__ wff2T,
                            const float* __restrict__ x,
                            const float* __restrict__ g1, const float* __restrict__ b1,
                            const float* __restrict__ g2, const float* __restrict__ b2,
                            bf16* __restrict__ a, bf16* __restrict__ f) {
    __shared__ __align__(16) float smem[12672 + 512 + 64];
    const int tid = threadIdx.x;
    int g = blockIdx.x;
    if (g < 1536) {
        float (*tl)[33] = (float (*)[33])smem;
        const float* in; bf16* out; int R, Cc, bx, by;
        if (g < 288)       { in = wqkv; out = wqkvT; R = 384;  Cc = 768;  bx = g % 24; by = g / 24; }
        else if (g < 384)  { g -= 288; in = wout; out = woutT; R = 256;  Cc = 384;  bx = g % 12; by = g / 12; }
        else if (g < 960)  { g -= 384; in = wff1; out = wff1T; R = 384;  Cc = 1536; bx = g % 48; by = g / 48; }
        else               { g -= 960; in = wff2; out = wff2T; R = 1536; Cc = 384;  bx = g % 12; by = g / 12; }
        const int c0 = bx * 32, r0 = by * 32;
        const int cl = tid & 31, r8 = tid >> 5;
#pragma unroll
        for (int k = 0; k < 4; k++) {
            int r = k * 8 + r8;
            tl[r][cl] = in[(size_t)(r0 + r) * Cc + c0 + cl];
        }
        __syncthreads();
#pragma unroll
        for (int k = 0; k < 4; k++) {
            int cc = k * 8 + r8;
            out[(size_t)(c0 + cc) * R + r0 + cl] = (bf16)tl[cl][cc];
        }
        return;
    }
    g -= 1536;
    float (*tile)[33] = (float (*)[33])smem;
    float (*S)[32]  = (float (*)[32])(smem + 12672);
    float (*SS)[32] = (float (*)[32])(smem + 12928);
    float* Mn = smem + 13184;
    float* Rs = smem + 13216;
    const int bb = g >> 3;
    const int i0 = (g & 7) * 32;
    {
        const int i_l = tid & 31, c_l = tid >> 5;
        const size_t base = (size_t)bb * 384 * 256 + i0 + i_l;
#pragma unroll 6
        for (int c = c_l; c < 384; c += 8)
            tile[c][i_l] = x[base + (size_t)c * 256];
    }
    __syncthreads();
    {
        const int i_s = tid & 31, p = tid >> 5;
        float s = 0.f, ss = 0.f;
#pragma unroll 6
        for (int j = 0; j < 48; j++) {
            float v = tile[p * 48 + j][i_s];
            s += v; ss += v * v;
        }
        S[p][i_s] = s; SS[p][i_s] = ss;
    }
    __syncthreads();
    if (tid < 32) {
        float t1 = 0.f, t2 = 0.f;
#pragma unroll
        for (int p = 0; p < 8; p++) { t1 += S[p][tid]; t2 += SS[p][tid]; }
        float mean = t1 * (1.0f / 384.0f);
        float var  = t2 * (1.0f / 384.0f) - mean * mean;
        Mn[tid] = mean;
        Rs[tid] = rsqrtf(var + 1e-5f);
    }
    __syncthreads();
    const int lane = tid & 63, w = tid >> 6;
#pragma unroll
    for (int rr = 0; rr < 8; rr++) {
        const int i = w * 8 + rr;
        const float mean = Mn[i], rstd = Rs[i];
        const size_t orow = ((size_t)bb * 256 + i0 + i) * 384;
#pragma unroll
        for (int pass = 0; pass < 6; pass++) {
            const int c = pass * 64 + lane;
            float nh = (tile[c][i] - mean) * rstd;
            a[orow + c] = (bf16)(nh * g1[c] + b1[c]);
            f[orow + c] = (bf16)(nh * g2[c] + b2[c]);
        }
    }
}

// ---------------- GEMM variant 1 (R4-proven config; sigmoid-form gelu) ----------------
template <int EPI>
__launch_bounds__(256)
__global__ void gemm_bt(const bf16* __restrict__ A, const bf16* __restrict__ Bt,
                        const float* __restrict__ bias, bf16* __restrict__ C,
                        int M, int N, int K, int nx) {
    __shared__ bf16 lds[16384];
    bf16* lA = lds;
    bf16* lB = lds + 4096;
    const int tid = threadIdx.x;
    const int g = blockIdx.x;
    const int x = (g >> 3) % nx;
    const int y = (g & 7) + 8 * (g / (8 * nx));
    const int m0 = y * 128, n0 = x * 128;
    const int lane = tid & 63, w = tid >> 6;
    const int l16 = lane & 15, quad = lane >> 4;
    const int wm = (w & 1) * 64, wn = (w >> 1) * 64;

    f32x4 zero = {0.f, 0.f, 0.f, 0.f};
    f32x4 acc[4][4];
#pragma unroll
    for (int i = 0; i < 4; i++)
#pragma unroll
        for (int j = 0; j < 4; j++) acc[i][j] = zero;

    const int c0 = tid, c1 = tid + 256;
    const int r0 = c0 >> 2, k0c = (c0 & 3) * 8;
    const int r1 = c1 >> 2, k1c = (c1 & 3) * 8;
    const bf16* Abase = A + (size_t)m0 * K;
    const bf16* Bbase = Bt + (size_t)n0 * K;

    for (int kb = 0; kb < K; kb += 32) {
        gll16(Abase + (size_t)r0 * K + kb + k0c, lA + c0 * 8);
        gll16(Abase + (size_t)r1 * K + kb + k1c, lA + c1 * 8);
        gll16(Bbase + (size_t)r0 * K + kb + k0c, lB + c0 * 8);
        gll16(Bbase + (size_t)r1 * K + kb + k1c, lB + c1 * 8);
        __syncthreads();
        bf16x8 af[4], bfr[4];
#pragma unroll
        for (int i = 0; i < 4; i++)
            af[i] = *(const bf16x8*)(lA + (wm + i * 16 + l16) * 32 + quad * 8);
#pragma unroll
        for (int j = 0; j < 4; j++)
            bfr[j] = *(const bf16x8*)(lB + (wn + j * 16 + l16) * 32 + quad * 8);
#pragma unroll
        for (int i = 0; i < 4; i++)
#pragma unroll
            for (int j = 0; j < 4; j++)
                acc[i][j] = __builtin_amdgcn_mfma_f32_16x16x32_bf16(af[i], bfr[j], acc[i][j], 0, 0, 0);
        __syncthreads();
    }

#pragma unroll
    for (int j = 0; j < 4; j++) {
        const int col = wn + j * 16 + l16;
        float bv = 0.f;
        if (EPI >= 1) bv = bias[n0 + col];
#pragma unroll
        for (int i = 0; i < 4; i++) {
            const int row0 = wm + i * 16 + quad * 4;
#pragma unroll
            for (int r = 0; r < 4; r++) {
                float v = acc[i][j][r] + bv;
                if (EPI == 2) v = gelu_f(v);
                lds[(row0 + r) * 128 + col] = (bf16)v;
            }
        }
    }
    __syncthreads();
#pragma unroll
    for (int it = 0; it < 8; it++) {
        const int ch = tid + it * 256;
        const int row = ch >> 4, cc = (ch & 15) * 8;
        *(bf16x8*)(C + (size_t)(m0 + row) * N + n0 + cc) = *(const bf16x8*)(lds + row * 128 + cc);
    }
}

// ---------------- 64x64-tile core for the N=384 GEMMs (grid 1536 = 6 blocks/CU) ----------
// 4 waves of 32x32 (acc[2][2]); staging A 64x32 + B 64x32 per iter (2 gll16/thread).
#define GEMM6464_PROLOGUE_AND_KLOOP                                                 \
    const int tid = threadIdx.x;                                                    \
    const int g = blockIdx.x;                                                       \
    const int x_ = (g >> 3) % nx;                                                   \
    const int y_ = (g & 7) + 8 * (g / (8 * nx));                                    \
    const int m0 = y_ * 64, n0 = x_ * 64;                                           \
    const int lane = tid & 63, w = tid >> 6;                                        \
    const int l16 = lane & 15, quad = lane >> 4;                                    \
    const int wm = (w & 1) * 32, wn = (w >> 1) * 32;                                \
    f32x4 zero = {0.f, 0.f, 0.f, 0.f};                                              \
    f32x4 acc[2][2];                                                                \
    _Pragma("unroll") for (int i = 0; i < 2; i++)                                   \
        _Pragma("unroll") for (int j = 0; j < 2; j++) acc[i][j] = zero;             \
    const int rs = tid >> 2, k8 = (tid & 3) * 8;                                    \
    const bf16* Abase = A + (size_t)m0 * K;                                         \
    const bf16* Bbase = Bt + (size_t)n0 * K;                                        \
    for (int kb = 0; kb < K; kb += 32) {                                            \
        gll16(Abase + (size_t)rs * K + kb + k8, lA + tid * 8);                      \
        gll16(Bbase + (size_t)rs * K + kb + k8, lB + tid * 8);                      \
        __syncthreads();                                                            \
        bf16x8 af[2], bfr[2];                                                       \
        _Pragma("unroll") for (int i = 0; i < 2; i++)                               \
            af[i] = *(const bf16x8*)(lA + (wm + i * 16 + l16) * 32 + quad * 8);     \
        _Pragma("unroll") for (int j = 0; j < 2; j++)                               \
            bfr[j] = *(const bf16x8*)(lB + (wn + j * 16 + l16) * 32 + quad * 8);    \
        _Pragma("unroll") for (int i = 0; i < 2; i++)                               \
            _Pragma("unroll") for (int j = 0; j < 2; j++)                           \
                acc[i][j] = __builtin_amdgcn_mfma_f32_16x16x32_bf16(af[i], bfr[j], acc[i][j], 0, 0, 0); \
        __syncthreads();                                                            \
    }

// ---------------- variant 2 (out-proj): TRANSPOSED attn_t[b][c][i] bf16, 64x64 ----------
__launch_bounds__(256)
__global__ void gemm_bt_tr64(const bf16* __restrict__ A, const bf16* __restrict__ Bt,
                             const float* __restrict__ bias, bf16* __restrict__ Ct,
                             int M, int N, int K, int nx) {
    __shared__ bf16 lds[8192];           // staging lA/lB 4KB+4KB; epilogue tile[64][68] aliases
    bf16* lA = lds;
    bf16* lB = lds + 2048;
    GEMM6464_PROLOGUE_AND_KLOOP
#pragma unroll
    for (int j = 0; j < 2; j++) {
        const int col = wn + j * 16 + l16;
        const float bv = bias[n0 + col];
#pragma unroll
        for (int i = 0; i < 2; i++) {
            const int row0 = wm + i * 16 + quad * 4;
#pragma unroll
            for (int r = 0; r < 4; r++)
                lds[col * 68 + row0 + r] = (bf16)(acc[i][j][r] + bv);
        }
    }
    __syncthreads();
    const int b = m0 >> 8, ib = m0 & 255;
#pragma unroll
    for (int it = 0; it < 2; it++) {
        const int ch = tid + it * 256;
        const int cl = ch >> 3, ic = (ch & 7) * 8;
        *(bf16x8*)(Ct + ((size_t)(b * 384 + n0 + cl) * 256 + ib + ic)) =
            *(const bf16x8*)(lds + cl * 68 + ic);
    }
}

// ---------------- variant 3 (ff2 + residual): out[b][c][i] = x + attn_t + (A@Bt^T+bias) -----
__launch_bounds__(256)
__global__ void gemm_bt_final64(const bf16* __restrict__ A, const bf16* __restrict__ Bt,
                                const float* __restrict__ bias,
                                const float* __restrict__ xres, const bf16* __restrict__ attn_t,
                                float* __restrict__ out, int M, int N, int K, int nx) {
    __shared__ bf16 lds[8192];
    bf16* lA = lds;
    bf16* lB = lds + 2048;
    GEMM6464_PROLOGUE_AND_KLOOP
#pragma unroll
    for (int j = 0; j < 2; j++) {
        const int col = wn + j * 16 + l16;
        const float bv = bias[n0 + col];
#pragma unroll
        for (int i = 0; i < 2; i++) {
            const int row0 = wm + i * 16 + quad * 4;
#pragma unroll
            for (int r = 0; r < 4; r++)
                lds[col * 68 + row0 + r] = (bf16)(acc[i][j][r] + bv);
        }
    }
    __syncthreads();
    const int b = m0 >> 8, ib = m0 & 255;
#pragma unroll
    for (int it = 0; it < 2; it++) {
        const int ch = tid + it * 256;
        const int cl = ch >> 3, ic = (ch & 7) * 8;
        const size_t base = (size_t)(b * 384 + n0 + cl) * 256 + ib + ic;
        bf16x8 ff = *(const bf16x8*)(lds + cl * 68 + ic);
        bf16x8 at = *(const bf16x8*)(attn_t + base);
#pragma unroll
        for (int e = 0; e < 8; e++)
            out[base + e] = xres[base + e] + (float)at[e] + (float)ff[e];
    }
}

// ---------------- fused attention: one block per (b,h); qc loop inside ----------------
__launch_bounds__(256)
__global__ void attn_kernel(const bf16* __restrict__ qkv,
                            const float* __restrict__ btab,
                            bf16* __restrict__ o) {
    __shared__ float sbias[961];
    __shared__ __align__(16) bf16 sK[256 * 32];        // [k][d] for B-frags
    __shared__ __align__(16) bf16 sVt[32][264];        // [d][k]
    __shared__ __align__(16) bf16 sP[4][16][264];
    const int tid = threadIdx.x;
    const int g = blockIdx.x;
    const int h  = (g >> 3) & 7;
    const int bb = (g & 7) + 8 * (g >> 6);
    const int lane = tid & 63, w = tid >> 6;
    const int l16 = lane & 15, quad = lane >> 4;
    const size_t qkvb = (size_t)bb * 256 * 768;
    const bf16* Qbase = qkv + qkvb + h * 32;
    const bf16* Kbase = qkv + qkvb + 256 + h * 32;
    const bf16* Vbase = qkv + qkvb + 512 + h * 32;

    for (int e = tid; e < 961; e += 256) sbias[e] = btab[e * 8 + h];
#pragma unroll
    for (int it = 0; it < 4; it++) {
        const int ch = it * 256 + tid;
        const int row = ch >> 2, d8 = (ch & 3) * 8;
        gll16(Kbase + (size_t)row * 768 + d8, sK + ch * 8);
    }
#pragma unroll
    for (int it = 0; it < 4; it++) {
        const int ch = it * 256 + tid;
        const int k = ch >> 2, d8 = (ch & 3) * 8;
        bf16x8 vv = *(const bf16x8*)(Vbase + (size_t)k * 768 + d8);
#pragma unroll
        for (int j = 0; j < 8; j++)
            sVt[d8 + j][k] = vv[j];
    }
    __syncthreads();

    f32x4 zero = {0.f, 0.f, 0.f, 0.f};
    for (int qc = 0; qc < 4; qc++) {
        const int qbase = qc * 64 + w * 16;
        bf16x8 qf = *(const bf16x8*)(Qbase + (size_t)(qbase + l16) * 768 + quad * 8);
        f32x4 s[16];
#pragma unroll
        for (int kt = 0; kt < 16; kt++) {
            bf16x8 kf = *(const bf16x8*)(sK + (kt * 16 + l16) * 32 + quad * 8);
            s[kt] = __builtin_amdgcn_mfma_f32_16x16x32_bf16(qf, kf, zero, 0, 0, 0);
        }
        const int qi0 = qbase + quad * 4;
        float mx[4] = {-1e30f, -1e30f, -1e30f, -1e30f};
#pragma unroll
        for (int kt = 0; kt < 16; kt++) {
            const int j = kt * 16 + l16;
            const int yj = j >> 4, xj = j & 15;
#pragma unroll
            for (int r = 0; r < 4; r++) {
                const int q = qi0 + r;
                const int tix = ((q >> 4) - yj + 15) * 31 + ((q & 15) - xj + 15);
                float v = s[kt][r] * 0.17677669529663687f + sbias[tix];
                s[kt][r] = v;
                mx[r] = fmaxf(mx[r], v);
            }
        }
#pragma unroll
        for (int r = 0; r < 4; r++)
            for (int msk = 1; msk < 16; msk <<= 1)
                mx[r] = fmaxf(mx[r], __shfl_xor(mx[r], msk, 64));
        float sum[4] = {0.f, 0.f, 0.f, 0.f};
#pragma unroll
        for (int kt = 0; kt < 16; kt++)
#pragma unroll
            for (int r = 0; r < 4; r++) {
                float e = __expf(s[kt][r] - mx[r]);
                s[kt][r] = e;
                sum[r] += e;
            }
#pragma unroll
        for (int r = 0; r < 4; r++) {
            for (int msk = 1; msk < 16; msk <<= 1)
                sum[r] += __shfl_xor(sum[r], msk, 64);
            sum[r] = 1.0f / sum[r];
        }
#pragma unroll
        for (int kt = 0; kt < 16; kt++)
#pragma unroll
            for (int r = 0; r < 4; r++)
                sP[w][quad * 4 + r][kt * 16 + l16] = (bf16)(s[kt][r] * sum[r]);
        f32x4 oacc[2];
        oacc[0] = zero; oacc[1] = zero;
#pragma unroll
        for (int ks = 0; ks < 8; ks++) {
            bf16x8 pf = *(const bf16x8*)(&sP[w][l16][ks * 32 + quad * 8]);
#pragma unroll
            for (int dt = 0; dt < 2; dt++) {
                bf16x8 vf = *(const bf16x8*)(&sVt[dt * 16 + l16][ks * 32 + quad * 8]);
                oacc[dt] = __builtin_amdgcn_mfma_f32_16x16x32_bf16(pf, vf, oacc[dt], 0, 0, 0);
            }
        }
#pragma unroll
        for (int dt = 0; dt < 2; dt++)
#pragma unroll
            for (int r = 0; r < 4; r++)
                o[(size_t)(bb * 256 + qbase + quad * 4 + r) * 256 + h * 32 + dt * 16 + l16] = (bf16)oacc[dt][r];
    }
}

extern "C" void kernel_launch(void* const* d_in, const int* in_sizes, int n_in,
                              void* d_out, int out_size, void* d_ws, size_t ws_size,
                              hipStream_t stream) {
    const float* x    = (const float*)d_in[0];
    const float* g1   = (const float*)d_in[1];
    const float* b1   = (const float*)d_in[2];
    const float* wqkv = (const float*)d_in[3];
    const float* btab = (const float*)d_in[4];
    const float* wout = (const float*)d_in[5];
    const float* bout = (const float*)d_in[6];
    const float* g2   = (const float*)d_in[7];
    const float* b2   = (const float*)d_in[8];
    const float* wff1 = (const float*)d_in[9];
    const float* bff1 = (const float*)d_in[10];
    const float* wff2 = (const float*)d_in[11];
    const float* bff2 = (const float*)d_in[12];
    float* out = (float*)d_out;

    bf16* ws = (bf16*)d_ws;
    const size_t NA = 6291456;                 // 16384*384
    bf16* wqkvT = ws;                          // [768,384]
    bf16* woutT = wqkvT + 294912;              // [384,256]
    bf16* wff1T = woutT + 98304;               // [1536,384]
    bf16* wff2T = wff1T + 589824;              // [384,1536]
    bf16* f_buf    = ws + 1572864;             // [16384,384]
    bf16* attn_t   = f_buf + NA;               // [64,384,256] (transposed attn out)
    bf16* R        = attn_t + NA;              // reuse region
    bf16* a_buf    = R;                        // [16384,384]   live ln -> qkvgemm
    bf16* qkv_buf  = R + NA;                   // [16384,768]   live qkvgemm -> attn
    bf16* o_buf    = R;                        // [16384,256]   live attn -> outproj
    bf16* ffh_buf  = R;                        // [16384,1536]  live ff1 -> ff2

    dim3 b256(256);
    prep_kernel<<<2048, b256, 0, stream>>>(wqkv, wout, wff1, wff2, wqkvT, woutT, wff1T, wff2T,
                                           x, g1, b1, g2, b2, a_buf, f_buf);

    gemm_bt<0><<<6 * 128, b256, 0, stream>>>(a_buf, wqkvT, nullptr, qkv_buf, 16384, 768, 384, 6);
    attn_kernel<<<512, b256, 0, stream>>>(qkv_buf, btab, o_buf);
    gemm_bt_tr64<<<6 * 256, b256, 0, stream>>>(o_buf, woutT, bout, attn_t, 16384, 384, 256, 6);
    gemm_bt<2><<<12 * 128, b256, 0, stream>>>(f_buf, wff1T, bff1, ffh_buf, 16384, 1536, 384, 12);
    gemm_bt_final64<<<6 * 256, b256, 0, stream>>>(ffh_buf, wff2T, bff2, x, attn_t, out,
                                                  16384, 384, 1536, 6);
}

// Round 12
// 227.840 us; speedup vs baseline: 1.0649x; 1.0649x over previous
//
#include <hip/hip_runtime.h>

typedef __bf16 bf16;
typedef __bf16 bf16x8 __attribute__((ext_vector_type(8)));
typedef float f32x4 __attribute__((ext_vector_type(4)));

__device__ __forceinline__ void gll16(const void* g, void* l) {
    __builtin_amdgcn_global_load_lds((const __attribute__((address_space(1))) void*)g,
                                     (__attribute__((address_space(3))) void*)l, 16, 0, 0);
}

// gelu via sigmoid identity: 0.5(1+tanh(u)) == sigmoid(2u). 8 VALU ops, no branches.
__device__ __forceinline__ float gelu_f(float v) {
    float x2 = v * v;
    float sn = v * fmaf(-0.0713540072f, x2, -1.5957691216f);   // -2u
    float e  = __expf(sn);
    return v * __builtin_amdgcn_rcpf(1.0f + e);
}

// ---------------- prep: 4 weight transposes (blocks 0..1535) + dual LN (blocks 1536..2047) ----
__launch_bounds__(256)
__global__ void prep_kernel(const float* __restrict__ wqkv, const float* __restrict__ wout,
                            const float* __restrict__ wff1, const float* __restrict__ wff2,
                            bf16* __restrict__ wqkvT, bf16* __restrict__ woutT,
                            bf16* __restrict__ wff1T, bf16* __restrict__ wff2T,
                            const float* __restrict__ x,
                            const float* __restrict__ g1, const float* __restrict__ b1,
                            const float* __restrict__ g2, const float* __restrict__ b2,
                            bf16* __restrict__ a, bf16* __restrict__ f) {
    __shared__ __align__(16) float smem[12672 + 512 + 64];
    const int tid = threadIdx.x;
    int g = blockIdx.x;
    if (g < 1536) {
        float (*tl)[33] = (float (*)[33])smem;
        const float* in; bf16* out; int R, Cc, bx, by;
        if (g < 288)       { in = wqkv; out = wqkvT; R = 384;  Cc = 768;  bx = g % 24; by = g / 24; }
        else if (g < 384)  { g -= 288; in = wout; out = woutT; R = 256;  Cc = 384;  bx = g % 12; by = g / 12; }
        else if (g < 960)  { g -= 384; in = wff1; out = wff1T; R = 384;  Cc = 1536; bx = g % 48; by = g / 48; }
        else               { g -= 960; in = wff2; out = wff2T; R = 1536; Cc = 384;  bx = g % 12; by = g / 12; }
        const int c0 = bx * 32, r0 = by * 32;
        const int cl = tid & 31, r8 = tid >> 5;
#pragma unroll
        for (int k = 0; k < 4; k++) {
            int r = k * 8 + r8;
            tl[r][cl] = in[(size_t)(r0 + r) * Cc + c0 + cl];
        }
        __syncthreads();
#pragma unroll
        for (int k = 0; k < 4; k++) {
            int cc = k * 8 + r8;
            out[(size_t)(c0 + cc) * R + r0 + cl] = (bf16)tl[cl][cc];
        }
        return;
    }
    g -= 1536;
    float (*tile)[33] = (float (*)[33])smem;
    float (*S)[32]  = (float (*)[32])(smem + 12672);
    float (*SS)[32] = (float (*)[32])(smem + 12928);
    float* Mn = smem + 13184;
    float* Rs = smem + 13216;
    const int bb = g >> 3;
    const int i0 = (g & 7) * 32;
    {
        const int i_l = tid & 31, c_l = tid >> 5;
        const size_t base = (size_t)bb * 384 * 256 + i0 + i_l;
#pragma unroll 6
        for (int c = c_l; c < 384; c += 8)
            tile[c][i_l] = x[base + (size_t)c * 256];
    }
    __syncthreads();
    {
        const int i_s = tid & 31, p = tid >> 5;
        float s = 0.f, ss = 0.f;
#pragma unroll 6
        for (int j = 0; j < 48; j++) {
            float v = tile[p * 48 + j][i_s];
            s += v; ss += v * v;
        }
        S[p][i_s] = s; SS[p][i_s] = ss;
    }
    __syncthreads();
    if (tid < 32) {
        float t1 = 0.f, t2 = 0.f;
#pragma unroll
        for (int p = 0; p < 8; p++) { t1 += S[p][tid]; t2 += SS[p][tid]; }
        float mean = t1 * (1.0f / 384.0f);
        float var  = t2 * (1.0f / 384.0f) - mean * mean;
        Mn[tid] = mean;
        Rs[tid] = rsqrtf(var + 1e-5f);
    }
    __syncthreads();
    const int lane = tid & 63, w = tid >> 6;
#pragma unroll
    for (int rr = 0; rr < 8; rr++) {
        const int i = w * 8 + rr;
        const float mean = Mn[i], rstd = Rs[i];
        const size_t orow = ((size_t)bb * 256 + i0 + i) * 384;
#pragma unroll
        for (int pass = 0; pass < 6; pass++) {
            const int c = pass * 64 + lane;
            float nh = (tile[c][i] - mean) * rstd;
            a[orow + c] = (bf16)(nh * g1[c] + b1[c]);
            f[orow + c] = (bf16)(nh * g2[c] + b2[c]);
        }
    }
}

// ---------------- GEMM variant 1 (R4-proven config; sigmoid-form gelu) ----------------
template <int EPI>
__launch_bounds__(256)
__global__ void gemm_bt(const bf16* __restrict__ A, const bf16* __restrict__ Bt,
                        const float* __restrict__ bias, bf16* __restrict__ C,
                        int M, int N, int K, int nx) {
    __shared__ bf16 lds[16384];
    bf16* lA = lds;
    bf16* lB = lds + 4096;
    const int tid = threadIdx.x;
    const int g = blockIdx.x;
    const int x = (g >> 3) % nx;
    const int y = (g & 7) + 8 * (g / (8 * nx));
    const int m0 = y * 128, n0 = x * 128;
    const int lane = tid & 63, w = tid >> 6;
    const int l16 = lane & 15, quad = lane >> 4;
    const int wm = (w & 1) * 64, wn = (w >> 1) * 64;

    f32x4 zero = {0.f, 0.f, 0.f, 0.f};
    f32x4 acc[4][4];
#pragma unroll
    for (int i = 0; i < 4; i++)
#pragma unroll
        for (int j = 0; j < 4; j++) acc[i][j] = zero;

    const int c0 = tid, c1 = tid + 256;
    const int r0 = c0 >> 2, k0c = (c0 & 3) * 8;
    const int r1 = c1 >> 2, k1c = (c1 & 3) * 8;
    const bf16* Abase = A + (size_t)m0 * K;
    const bf16* Bbase = Bt + (size_t)n0 * K;

    for (int kb = 0; kb < K; kb += 32) {
        gll16(Abase + (size_t)r0 * K + kb + k0c, lA + c0 * 8);
        gll16(Abase + (size_t)r1 * K + kb + k1c, lA + c1 * 8);
        gll16(Bbase + (size_t)r0 * K + kb + k0c, lB + c0 * 8);
        gll16(Bbase + (size_t)r1 * K + kb + k1c, lB + c1 * 8);
        __syncthreads();
        bf16x8 af[4], bfr[4];
#pragma unroll
        for (int i = 0; i < 4; i++)
            af[i] = *(const bf16x8*)(lA + (wm + i * 16 + l16) * 32 + quad * 8);
#pragma unroll
        for (int j = 0; j < 4; j++)
            bfr[j] = *(const bf16x8*)(lB + (wn + j * 16 + l16) * 32 + quad * 8);
#pragma unroll
        for (int i = 0; i < 4; i++)
#pragma unroll
            for (int j = 0; j < 4; j++)
                acc[i][j] = __builtin_amdgcn_mfma_f32_16x16x32_bf16(af[i], bfr[j], acc[i][j], 0, 0, 0);
        __syncthreads();
    }

#pragma unroll
    for (int j = 0; j < 4; j++) {
        const int col = wn + j * 16 + l16;
        float bv = 0.f;
        if (EPI >= 1) bv = bias[n0 + col];
#pragma unroll
        for (int i = 0; i < 4; i++) {
            const int row0 = wm + i * 16 + quad * 4;
#pragma unroll
            for (int r = 0; r < 4; r++) {
                float v = acc[i][j][r] + bv;
                if (EPI == 2) v = gelu_f(v);
                lds[(row0 + r) * 128 + col] = (bf16)v;
            }
        }
    }
    __syncthreads();
#pragma unroll
    for (int it = 0; it < 8; it++) {
        const int ch = tid + it * 256;
        const int row = ch >> 4, cc = (ch & 15) * 8;
        *(bf16x8*)(C + (size_t)(m0 + row) * N + n0 + cc) = *(const bf16x8*)(lds + row * 128 + cc);
    }
}

// ---------------- 128x64-tile core, BK=64 via twin BK=32 buffers (N=384 GEMMs) -----------
// 4 waves of 64x32 (acc[4][2]); per K-step: 6 gll16/thread in flight, ONE barrier drain,
// 16 MFMA/wave. Halves barrier-drain count vs R10 while keeping the proven lane-linear
// BK=32 LDS layout per buffer. K must be divisible by 64.
#define GEMM64_PROLOGUE_AND_KLOOP                                                   \
    const int tid = threadIdx.x;                                                    \
    const int g = blockIdx.x;                                                       \
    const int x_ = (g >> 3) % nx;                                                   \
    const int y_ = (g & 7) + 8 * (g / (8 * nx));                                    \
    const int m0 = y_ * 128, n0 = x_ * 64;                                          \
    const int lane = tid & 63, w = tid >> 6;                                        \
    const int l16 = lane & 15, quad = lane >> 4;                                    \
    const int wm = (w & 1) * 64, wn = (w >> 1) * 32;                                \
    f32x4 zero = {0.f, 0.f, 0.f, 0.f};                                              \
    f32x4 acc[4][2];                                                                \
    _Pragma("unroll") for (int i = 0; i < 4; i++)                                   \
        _Pragma("unroll") for (int j = 0; j < 2; j++) acc[i][j] = zero;             \
    const int c0 = tid, c1 = tid + 256;                                             \
    const int r0 = c0 >> 2, k0c = (c0 & 3) * 8;                                     \
    const int r1 = c1 >> 2, k1c = (c1 & 3) * 8;                                     \
    const bf16* Abase = A + (size_t)m0 * K;                                         \
    const bf16* Bbase = Bt + (size_t)n0 * K;                                        \
    for (int kb = 0; kb < K; kb += 64) {                                            \
        gll16(Abase + (size_t)r0 * K + kb + k0c,      lA0 + c0 * 8);                \
        gll16(Abase + (size_t)r1 * K + kb + k1c,      lA0 + c1 * 8);                \
        gll16(Abase + (size_t)r0 * K + kb + 32 + k0c, lA1 + c0 * 8);                \
        gll16(Abase + (size_t)r1 * K + kb + 32 + k1c, lA1 + c1 * 8);                \
        gll16(Bbase + (size_t)r0 * K + kb + k0c,      lB0 + c0 * 8);                \
        gll16(Bbase + (size_t)r0 * K + kb + 32 + k0c, lB1 + c0 * 8);                \
        __syncthreads();                                                            \
        bf16x8 af[4], bfr[2];                                                       \
        _Pragma("unroll") for (int i = 0; i < 4; i++)                               \
            af[i] = *(const bf16x8*)(lA0 + (wm + i * 16 + l16) * 32 + quad * 8);    \
        _Pragma("unroll") for (int j = 0; j < 2; j++)                               \
            bfr[j] = *(const bf16x8*)(lB0 + (wn + j * 16 + l16) * 32 + quad * 8);   \
        _Pragma("unroll") for (int i = 0; i < 4; i++)                               \
            _Pragma("unroll") for (int j = 0; j < 2; j++)                           \
                acc[i][j] = __builtin_amdgcn_mfma_f32_16x16x32_bf16(af[i], bfr[j], acc[i][j], 0, 0, 0); \
        _Pragma("unroll") for (int i = 0; i < 4; i++)                               \
            af[i] = *(const bf16x8*)(lA1 + (wm + i * 16 + l16) * 32 + quad * 8);    \
        _Pragma("unroll") for (int j = 0; j < 2; j++)                               \
            bfr[j] = *(const bf16x8*)(lB1 + (wn + j * 16 + l16) * 32 + quad * 8);   \
        _Pragma("unroll") for (int i = 0; i < 4; i++)                               \
            _Pragma("unroll") for (int j = 0; j < 2; j++)                           \
                acc[i][j] = __builtin_amdgcn_mfma_f32_16x16x32_bf16(af[i], bfr[j], acc[i][j], 0, 0, 0); \
        __syncthreads();                                                            \
    }

// ---------------- variant 2 (out-proj): TRANSPOSED attn_t[b][c][i] bf16 -----------------
__launch_bounds__(256)
__global__ void gemm_bt_tr64(const bf16* __restrict__ A, const bf16* __restrict__ Bt,
                             const float* __restrict__ bias, bf16* __restrict__ Ct,
                             int M, int N, int K, int nx) {
    __shared__ bf16 lds[12288];          // 24 KB: lA0/lA1 4096 each, lB0/lB1 2048 each
    bf16* lA0 = lds;
    bf16* lA1 = lds + 4096;
    bf16* lB0 = lds + 8192;
    bf16* lB1 = lds + 10240;
    GEMM64_PROLOGUE_AND_KLOOP
    // epilogue: tile[col][row] stride 132, aliases staging (8448 <= 12288)
#pragma unroll
    for (int j = 0; j < 2; j++) {
        const int col = wn + j * 16 + l16;
        const float bv = bias[n0 + col];
#pragma unroll
        for (int i = 0; i < 4; i++) {
            const int row0 = wm + i * 16 + quad * 4;
#pragma unroll
            for (int r = 0; r < 4; r++)
                lds[col * 132 + row0 + r] = (bf16)(acc[i][j][r] + bv);
        }
    }
    __syncthreads();
    const int b = m0 >> 8, ib = m0 & 255;
#pragma unroll
    for (int it = 0; it < 4; it++) {
        const int ch = tid + it * 256;
        const int cl = ch >> 4, ic = (ch & 15) * 8;
        *(bf16x8*)(Ct + ((size_t)(b * 384 + n0 + cl) * 256 + ib + ic)) =
            *(const bf16x8*)(lds + cl * 132 + ic);
    }
}

// ---------------- variant 3 (ff2 + residual): out[b][c][i] = x + attn_t + (A@Bt^T+bias) -----
__launch_bounds__(256)
__global__ void gemm_bt_final64(const bf16* __restrict__ A, const bf16* __restrict__ Bt,
                                const float* __restrict__ bias,
                                const float* __restrict__ xres, const bf16* __restrict__ attn_t,
                                float* __restrict__ out, int M, int N, int K, int nx) {
    __shared__ bf16 lds[12288];
    bf16* lA0 = lds;
    bf16* lA1 = lds + 4096;
    bf16* lB0 = lds + 8192;
    bf16* lB1 = lds + 10240;
    GEMM64_PROLOGUE_AND_KLOOP
#pragma unroll
    for (int j = 0; j < 2; j++) {
        const int col = wn + j * 16 + l16;
        const float bv = bias[n0 + col];
#pragma unroll
        for (int i = 0; i < 4; i++) {
            const int row0 = wm + i * 16 + quad * 4;
#pragma unroll
            for (int r = 0; r < 4; r++)
                lds[col * 132 + row0 + r] = (bf16)(acc[i][j][r] + bv);
        }
    }
    __syncthreads();
    const int b = m0 >> 8, ib = m0 & 255;
#pragma unroll
    for (int it = 0; it < 4; it++) {
        const int ch = tid + it * 256;
        const int cl = ch >> 4, ic = (ch & 15) * 8;
        const size_t base = (size_t)(b * 384 + n0 + cl) * 256 + ib + ic;
        bf16x8 ff = *(const bf16x8*)(lds + cl * 132 + ic);
        bf16x8 at = *(const bf16x8*)(attn_t + base);
#pragma unroll
        for (int e = 0; e < 8; e++)
            out[base + e] = xres[base + e] + (float)at[e] + (float)ff[e];
    }
}

// ---------------- fused attention: one block per (b,h); qc loop inside ----------------
__launch_bounds__(256)
__global__ void attn_kernel(const bf16* __restrict__ qkv,
                            const float* __restrict__ btab,
                            bf16* __restrict__ o) {
    __shared__ float sbias[961];
    __shared__ __align__(16) bf16 sK[256 * 32];        // [k][d] for B-frags
    __shared__ __align__(16) bf16 sVt[32][264];        // [d][k]
    __shared__ __align__(16) bf16 sP[4][16][264];
    const int tid = threadIdx.x;
    const int g = blockIdx.x;
    const int h  = (g >> 3) & 7;
    const int bb = (g & 7) + 8 * (g >> 6);
    const int lane = tid & 63, w = tid >> 6;
    const int l16 = lane & 15, quad = lane >> 4;
    const size_t qkvb = (size_t)bb * 256 * 768;
    const bf16* Qbase = qkv + qkvb + h * 32;
    const bf16* Kbase = qkv + qkvb + 256 + h * 32;
    const bf16* Vbase = qkv + qkvb + 512 + h * 32;

    for (int e = tid; e < 961; e += 256) sbias[e] = btab[e * 8 + h];
#pragma unroll
    for (int it = 0; it < 4; it++) {
        const int ch = it * 256 + tid;
        const int row = ch >> 2, d8 = (ch & 3) * 8;
        gll16(Kbase + (size_t)row * 768 + d8, sK + ch * 8);
    }
#pragma unroll
    for (int it = 0; it < 4; it++) {
        const int ch = it * 256 + tid;
        const int k = ch >> 2, d8 = (ch & 3) * 8;
        bf16x8 vv = *(const bf16x8*)(Vbase + (size_t)k * 768 + d8);
#pragma unroll
        for (int j = 0; j < 8; j++)
            sVt[d8 + j][k] = vv[j];
    }
    __syncthreads();

    f32x4 zero = {0.f, 0.f, 0.f, 0.f};
    for (int qc = 0; qc < 4; qc++) {
        const int qbase = qc * 64 + w * 16;
        bf16x8 qf = *(const bf16x8*)(Qbase + (size_t)(qbase + l16) * 768 + quad * 8);
        f32x4 s[16];
#pragma unroll
        for (int kt = 0; kt < 16; kt++) {
            bf16x8 kf = *(const bf16x8*)(sK + (kt * 16 + l16) * 32 + quad * 8);
            s[kt] = __builtin_amdgcn_mfma_f32_16x16x32_bf16(qf, kf, zero, 0, 0, 0);
        }
        const int qi0 = qbase + quad * 4;
        float mx[4] = {-1e30f, -1e30f, -1e30f, -1e30f};
#pragma unroll
        for (int kt = 0; kt < 16; kt++) {
            const int j = kt * 16 + l16;
            const int yj = j >> 4, xj = j & 15;
#pragma unroll
            for (int r = 0; r < 4; r++) {
                const int q = qi0 + r;
                const int tix = ((q >> 4) - yj + 15) * 31 + ((q & 15) - xj + 15);
                float v = s[kt][r] * 0.17677669529663687f + sbias[tix];
                s[kt][r] = v;
                mx[r] = fmaxf(mx[r], v);
            }
        }
#pragma unroll
        for (int r = 0; r < 4; r++)
            for (int msk = 1; msk < 16; msk <<= 1)
                mx[r] = fmaxf(mx[r], __shfl_xor(mx[r], msk, 64));
        float sum[4] = {0.f, 0.f, 0.f, 0.f};
#pragma unroll
        for (int kt = 0; kt < 16; kt++)
#pragma unroll
            for (int r = 0; r < 4; r++) {
                float e = __expf(s[kt][r] - mx[r]);
                s[kt][r] = e;
                sum[r] += e;
            }
#pragma unroll
        for (int r = 0; r < 4; r++) {
            for (int msk = 1; msk < 16; msk <<= 1)
                sum[r] += __shfl_xor(sum[r], msk, 64);
            sum[r] = 1.0f / sum[r];
        }
#pragma unroll
        for (int kt = 0; kt < 16; kt++)
#pragma unroll
            for (int r = 0; r < 4; r++)
                sP[w][quad * 4 + r][kt * 16 + l16] = (bf16)(s[kt][r] * sum[r]);
        f32x4 oacc[2];
        oacc[0] = zero; oacc[1] = zero;
#pragma unroll
        for (int ks = 0; ks < 8; ks++) {
            bf16x8 pf = *(const bf16x8*)(&sP[w][l16][ks * 32 + quad * 8]);
#pragma unroll
            for (int dt = 0; dt < 2; dt++) {
                bf16x8 vf = *(const bf16x8*)(&sVt[dt * 16 + l16][ks * 32 + quad * 8]);
                oacc[dt] = __builtin_amdgcn_mfma_f32_16x16x32_bf16(pf, vf, oacc[dt], 0, 0, 0);
            }
        }
#pragma unroll
        for (int dt = 0; dt < 2; dt++)
#pragma unroll
            for (int r = 0; r < 4; r++)
                o[(size_t)(bb * 256 + qbase + quad * 4 + r) * 256 + h * 32 + dt * 16 + l16] = (bf16)oacc[dt][r];
    }
}

extern "C" void kernel_launch(void* const* d_in, const int* in_sizes, int n_in,
                              void* d_out, int out_size, void* d_ws, size_t ws_size,
                              hipStream_t stream) {
    const float* x    = (const float*)d_in[0];
    const float* g1   = (const float*)d_in[1];
    const float* b1   = (const float*)d_in[2];
    const float* wqkv = (const float*)d_in[3];
    const float* btab = (const float*)d_in[4];
    const float* wout = (const float*)d_in[5];
    const float* bout = (const float*)d_in[6];
    const float* g2   = (const float*)d_in[7];
    const float* b2   = (const float*)d_in[8];
    const float* wff1 = (const float*)d_in[9];
    const float* bff1 = (const float*)d_in[10];
    const float* wff2 = (const float*)d_in[11];
    const float* bff2 = (const float*)d_in[12];
    float* out = (float*)d_out;

    bf16* ws = (bf16*)d_ws;
    const size_t NA = 6291456;                 // 16384*384
    bf16* wqkvT = ws;                          // [768,384]
    bf16* woutT = wqkvT + 294912;              // [384,256]
    bf16* wff1T = woutT + 98304;               // [1536,384]
    bf16* wff2T = wff1T + 589824;              // [384,1536]
    bf16* f_buf    = ws + 1572864;             // [16384,384]
    bf16* attn_t   = f_buf + NA;               // [64,384,256] (transposed attn out)
    bf16* R        = attn_t + NA;              // reuse region
    bf16* a_buf    = R;                        // [16384,384]   live ln -> qkvgemm
    bf16* qkv_buf  = R + NA;                   // [16384,768]   live qkvgemm -> attn
    bf16* o_buf    = R;                        // [16384,256]   live attn -> outproj
    bf16* ffh_buf  = R;                        // [16384,1536]  live ff1 -> ff2

    dim3 b256(256);
    prep_kernel<<<2048, b256, 0, stream>>>(wqkv, wout, wff1, wff2, wqkvT, woutT, wff1T, wff2T,
                                           x, g1, b1, g2, b2, a_buf, f_buf);

    gemm_bt<0><<<6 * 128, b256, 0, stream>>>(a_buf, wqkvT, nullptr, qkv_buf, 16384, 768, 384, 6);
    attn_kernel<<<512, b256, 0, stream>>>(qkv_buf, btab, o_buf);
    gemm_bt_tr64<<<6 * 128, b256, 0, stream>>>(o_buf, woutT, bout, attn_t, 16384, 384, 256, 6);
    gemm_bt<2><<<12 * 128, b256, 0, stream>>>(f_buf, wff1T, bff1, ffh_buf, 16384, 1536, 384, 12);
    gemm_bt_final64<<<6 * 128, b256, 0, stream>>>(ffh_buf, wff2T, bff2, x, attn_t, out,
                                                  16384, 384, 1536, 6);
}